// Round 1
// baseline (282.628 us; speedup 1.0000x reference)
//
#include <hip/hip_runtime.h>
#include <math.h>

// Problem: B=32, T=512, F=64, O=64.
// delta[b,t,f] = (t==0) ? 0 : in[b,t,f]-in[b,t-1,f]
// x = (delta - bn_mean) * (bn_w * rsqrt(bn_var+1e-5)) + bn_b
// enc_o = x * enc_w[o] + enc_b[o]
// LIF scan over o: h = v + (enc_o - v)/2 ; s = (h>=1) ; v = s?0:h
// out[b,o,f,t] = s   (fp32, 0/1)
//
// One thread per (b,f,t-quad): t fastest across lanes -> coalesced float4
// stores on the 256MB output (dominant traffic). Input (4MB) reads are
// strided but L2-absorbed.

#define B_DIM 32
#define T_DIM 512
#define F_DIM 64
#define O_DIM 64

typedef float v4f __attribute__((ext_vector_type(4)));

__global__ __launch_bounds__(256) void delta_lif_kernel(
    const float* __restrict__ in,     // [B,T,F]
    const float* __restrict__ enc_w,  // [64] (O,1)
    const float* __restrict__ enc_b,  // [64]
    const float* __restrict__ bn_w,   // [1]
    const float* __restrict__ bn_b,   // [1]
    const float* __restrict__ bn_mean,// [1]
    const float* __restrict__ bn_var, // [1]
    float* __restrict__ out)          // [B,O,F,T]
{
#pragma clang fp contract(off)
    __shared__ float sW[O_DIM];
    __shared__ float sB[O_DIM];
    const int lt = threadIdx.x;
    if (lt < O_DIM) { sW[lt] = enc_w[lt]; sB[lt] = enc_b[lt]; }
    __syncthreads();

    // BatchNorm scalars — replicate reference op order exactly.
    // inv = bn_w * rsqrt(bn_var + eps); rsqrt computed correctly-rounded
    // via double 1/sqrt.
    const float vpe  = bn_var[0] + 1e-5f;
    const float r    = (float)(1.0 / sqrt((double)vpe));
    const float inv  = bn_w[0] * r;
    const float mean = bn_mean[0];
    const float bnb  = bn_b[0];

    const int tid = blockIdx.x * 256 + lt;   // 0 .. 262143
    const int t4  = tid & 127;               // T/4 = 128
    const int bf  = tid >> 7;
    const int f   = bf & 63;
    const int b   = bf >> 6;
    const int t0  = t4 << 2;

    // input: in[b, t, f] = in[b*T*F + t*F + f]
    const float* pin = in + b * (T_DIM * F_DIM) + f;
    const float c0 = pin[(t0 + 0) * F_DIM];
    const float c1 = pin[(t0 + 1) * F_DIM];
    const float c2 = pin[(t0 + 2) * F_DIM];
    const float c3 = pin[(t0 + 3) * F_DIM];
    const float p  = (t0 == 0) ? c0 : pin[(t0 - 1) * F_DIM];

    const float d0 = c0 - p;
    const float d1 = c1 - c0;
    const float d2 = c2 - c1;
    const float d3 = c3 - c2;

    const float x0 = (d0 - mean) * inv + bnb;
    const float x1 = (d1 - mean) * inv + bnb;
    const float x2 = (d2 - mean) * inv + bnb;
    const float x3 = (d3 - mean) * inv + bnb;

    float v0 = 0.0f, v1 = 0.0f, v2 = 0.0f, v3 = 0.0f;

    // out[b,o,f,t]: base = ((b*O + o)*F + f)*T + t
    float* pout = out + (b * O_DIM * F_DIM + f) * T_DIM + t0;

#pragma unroll 8
    for (int o = 0; o < O_DIM; ++o) {
        const float w  = sW[o];
        const float bb = sB[o];

        const float e0 = x0 * w + bb;
        const float e1 = x1 * w + bb;
        const float e2 = x2 * w + bb;
        const float e3 = x3 * w + bb;

        // h = v + (e - v)/2  ; division by 2 is exact, so *0.5f is identical
        const float h0 = v0 + (e0 - v0) * 0.5f;
        const float h1 = v1 + (e1 - v1) * 0.5f;
        const float h2 = v2 + (e2 - v2) * 0.5f;
        const float h3 = v3 + (e3 - v3) * 0.5f;

        const bool g0 = (h0 >= 1.0f);
        const bool g1 = (h1 >= 1.0f);
        const bool g2 = (h2 >= 1.0f);
        const bool g3 = (h3 >= 1.0f);

        v4f s;
        s.x = g0 ? 1.0f : 0.0f;
        s.y = g1 ? 1.0f : 0.0f;
        s.z = g2 ? 1.0f : 0.0f;
        s.w = g3 ? 1.0f : 0.0f;

        v0 = g0 ? 0.0f : h0;
        v1 = g1 ? 0.0f : h1;
        v2 = g2 ? 0.0f : h2;
        v3 = g3 ? 0.0f : h3;

        // streaming store: output is never re-read, skip L2 retention
        __builtin_nontemporal_store(s, (v4f*)(pout + o * (F_DIM * T_DIM)));
    }
}

extern "C" void kernel_launch(void* const* d_in, const int* in_sizes, int n_in,
                              void* d_out, int out_size, void* d_ws, size_t ws_size,
                              hipStream_t stream) {
    const float* in      = (const float*)d_in[0];
    const float* enc_w   = (const float*)d_in[1];
    const float* enc_b   = (const float*)d_in[2];
    const float* bn_w    = (const float*)d_in[3];
    const float* bn_b    = (const float*)d_in[4];
    const float* bn_mean = (const float*)d_in[5];
    const float* bn_var  = (const float*)d_in[6];
    float* out = (float*)d_out;

    // B*F*(T/4) threads = 32*64*128 = 262144 -> 1024 blocks of 256
    const int total = B_DIM * F_DIM * (T_DIM / 4);
    delta_lif_kernel<<<dim3(total / 256), dim3(256), 0, stream>>>(
        in, enc_w, enc_b, bn_w, bn_b, bn_mean, bn_var, out);
}

// Round 2
// 274.027 us; speedup vs baseline: 1.0314x; 1.0314x over previous
//
#include <hip/hip_runtime.h>
#include <math.h>

// Problem: B=32, T=512, F=64, O=64.
// delta[b,t,f] = (t==0) ? 0 : in[b,t,f]-in[b,t-1,f]
// x = (delta - bn_mean) * (bn_w * rsqrt(bn_var+1e-5)) + bn_b
// enc_o = x * enc_w[o] + enc_b[o]
// LIF scan over o: h = v + (enc_o - v)/2 ; s = (h>=1) ; v = s?0:h
// out[b,o,f,t] = s   (fp32, 0/1)
//
// One thread per (b,f,t-quad): t fastest across lanes -> coalesced float4
// stores on the 256MB output (dominant traffic). Input (4MB) reads are
// strided but L2-absorbed.
//
// R2: removed __builtin_nontemporal_store — nt bypasses L2 allocation, so
// the 64 scattered 1KB-chunk write streams per wave drained to HBM with
// poor row locality (~2.3 TB/s). Plain write-back lets L2 batch/sort lines
// (harness fill proves 6.4 TB/s on this buffer).

#define B_DIM 32
#define T_DIM 512
#define F_DIM 64
#define O_DIM 64

typedef float v4f __attribute__((ext_vector_type(4)));

__global__ __launch_bounds__(256) void delta_lif_kernel(
    const float* __restrict__ in,     // [B,T,F]
    const float* __restrict__ enc_w,  // [64] (O,1)
    const float* __restrict__ enc_b,  // [64]
    const float* __restrict__ bn_w,   // [1]
    const float* __restrict__ bn_b,   // [1]
    const float* __restrict__ bn_mean,// [1]
    const float* __restrict__ bn_var, // [1]
    float* __restrict__ out)          // [B,O,F,T]
{
#pragma clang fp contract(off)
    __shared__ float sW[O_DIM];
    __shared__ float sB[O_DIM];
    const int lt = threadIdx.x;
    if (lt < O_DIM) { sW[lt] = enc_w[lt]; sB[lt] = enc_b[lt]; }
    __syncthreads();

    // BatchNorm scalars — replicate reference op order exactly.
    const float vpe  = bn_var[0] + 1e-5f;
    const float r    = (float)(1.0 / sqrt((double)vpe));
    const float inv  = bn_w[0] * r;
    const float mean = bn_mean[0];
    const float bnb  = bn_b[0];

    const int tid = blockIdx.x * 256 + lt;   // 0 .. 262143
    const int t4  = tid & 127;               // T/4 = 128
    const int bf  = tid >> 7;
    const int f   = bf & 63;
    const int b   = bf >> 6;
    const int t0  = t4 << 2;

    // input: in[b, t, f] = in[b*T*F + t*F + f]
    const float* pin = in + b * (T_DIM * F_DIM) + f;
    const float c0 = pin[(t0 + 0) * F_DIM];
    const float c1 = pin[(t0 + 1) * F_DIM];
    const float c2 = pin[(t0 + 2) * F_DIM];
    const float c3 = pin[(t0 + 3) * F_DIM];
    const float p  = (t0 == 0) ? c0 : pin[(t0 - 1) * F_DIM];

    const float d0 = c0 - p;
    const float d1 = c1 - c0;
    const float d2 = c2 - c1;
    const float d3 = c3 - c2;

    const float x0 = (d0 - mean) * inv + bnb;
    const float x1 = (d1 - mean) * inv + bnb;
    const float x2 = (d2 - mean) * inv + bnb;
    const float x3 = (d3 - mean) * inv + bnb;

    float v0 = 0.0f, v1 = 0.0f, v2 = 0.0f, v3 = 0.0f;

    // out[b,o,f,t]: base = ((b*O + o)*F + f)*T + t
    float* pout = out + (b * O_DIM * F_DIM + f) * T_DIM + t0;

#pragma unroll 8
    for (int o = 0; o < O_DIM; ++o) {
        const float w  = sW[o];
        const float bb = sB[o];

        const float e0 = x0 * w + bb;
        const float e1 = x1 * w + bb;
        const float e2 = x2 * w + bb;
        const float e3 = x3 * w + bb;

        // h = v + (e - v)/2 ; /2 is exact, so *0.5f is identical
        const float h0 = v0 + (e0 - v0) * 0.5f;
        const float h1 = v1 + (e1 - v1) * 0.5f;
        const float h2 = v2 + (e2 - v2) * 0.5f;
        const float h3 = v3 + (e3 - v3) * 0.5f;

        const bool g0 = (h0 >= 1.0f);
        const bool g1 = (h1 >= 1.0f);
        const bool g2 = (h2 >= 1.0f);
        const bool g3 = (h3 >= 1.0f);

        v4f s;
        s.x = g0 ? 1.0f : 0.0f;
        s.y = g1 ? 1.0f : 0.0f;
        s.z = g2 ? 1.0f : 0.0f;
        s.w = g3 ? 1.0f : 0.0f;

        v0 = g0 ? 0.0f : h0;
        v1 = g1 ? 0.0f : h1;
        v2 = g2 ? 0.0f : h2;
        v3 = g3 ? 0.0f : h3;

        // plain write-back store: let L2 combine/sort lines before HBM drain
        *(v4f*)(pout + o * (F_DIM * T_DIM)) = s;
    }
}

extern "C" void kernel_launch(void* const* d_in, const int* in_sizes, int n_in,
                              void* d_out, int out_size, void* d_ws, size_t ws_size,
                              hipStream_t stream) {
    const float* in      = (const float*)d_in[0];
    const float* enc_w   = (const float*)d_in[1];
    const float* enc_b   = (const float*)d_in[2];
    const float* bn_w    = (const float*)d_in[3];
    const float* bn_b    = (const float*)d_in[4];
    const float* bn_mean = (const float*)d_in[5];
    const float* bn_var  = (const float*)d_in[6];
    float* out = (float*)d_out;

    // B*F*(T/4) threads = 32*64*128 = 262144 -> 1024 blocks of 256
    const int total = B_DIM * F_DIM * (T_DIM / 4);
    delta_lif_kernel<<<dim3(total / 256), dim3(256), 0, stream>>>(
        in, enc_w, enc_b, bn_w, bn_b, bn_mean, bn_var, out);
}